// Round 3
// baseline (74.332 us; speedup 1.0000x reference)
//
#include <hip/hip_runtime.h>

// Batched Tacrolimus PK derivative: out[i, :] = f(state[i, :], params[i])
// Memory-bound streaming kernel. 44 B in + 24 B out per row.
// 2 rows per thread: 3x float4 state loads, float2 param loads,
// 3x float4 non-temporal output stores.

typedef float f32x4 __attribute__((ext_vector_type(4)));
typedef float f32x2 __attribute__((ext_vector_type(2)));

__global__ __launch_bounds__(256) void TacrolimusPK_kernel2(
    const float* __restrict__ state,  // [n, 6]
    const float* __restrict__ Ktr,    // [n]
    const float* __restrict__ CL,     // [n]
    const float* __restrict__ Q,      // [n]
    const float* __restrict__ Vc,     // [n]
    const float* __restrict__ Vp,     // [n]
    float* __restrict__ out,          // [n, 6]
    int nPairs)                       // n/2 (n is even: 4194304)
{
    const int stride = gridDim.x * blockDim.x;
    for (int p = blockIdx.x * blockDim.x + threadIdx.x; p < nPairs; p += stride) {
        const f32x4* sp = reinterpret_cast<const f32x4*>(state) + 3ll * p;
        f32x4 a = sp[0];  // r0: A_depot, A_g1, A_g2, A_g3
        f32x4 b = sp[1];  // r0: A_c, A_p  | r1: A_depot, A_g1
        f32x4 c = sp[2];  // r1: A_g2, A_g3, A_c, A_p

        f32x2 ktr = reinterpret_cast<const f32x2*>(Ktr)[p];
        f32x2 cl  = reinterpret_cast<const f32x2*>(CL)[p];
        f32x2 q   = reinterpret_cast<const f32x2*>(Q)[p];
        f32x2 vc  = reinterpret_cast<const f32x2*>(Vc)[p];
        f32x2 vp  = reinterpret_cast<const f32x2*>(Vp)[p];

        // row 0
        float rvc0    = 1.0f / vc.x;
        float k_elim0 = cl.x * rvc0;
        float k12_0   = q.x * rvc0;
        float k21_0   = q.x / vp.x;
        f32x4 o0;
        o0.x = -ktr.x * a.x;
        o0.y = ktr.x * (a.x - a.y);
        o0.z = ktr.x * (a.y - a.z);
        o0.w = ktr.x * (a.z - a.w);
        float o1lo_x = ktr.x * a.w - (k_elim0 + k12_0) * b.x + k21_0 * b.y;
        float o1lo_y = k12_0 * b.x - k21_0 * b.y;

        // row 1
        float rvc1    = 1.0f / vc.y;
        float k_elim1 = cl.y * rvc1;
        float k12_1   = q.y * rvc1;
        float k21_1   = q.y / vp.y;
        f32x4 o2;
        float o1hi_x = -ktr.y * b.z;
        float o1hi_y = ktr.y * (b.z - b.w);
        o2.x = ktr.y * (b.w - c.x);
        o2.y = ktr.y * (c.x - c.y);
        o2.z = ktr.y * c.y - (k_elim1 + k12_1) * c.z + k21_1 * c.w;
        o2.w = k12_1 * c.z - k21_1 * c.w;

        f32x4 o1;
        o1.x = o1lo_x; o1.y = o1lo_y; o1.z = o1hi_x; o1.w = o1hi_y;

        f32x4* op = reinterpret_cast<f32x4*>(out) + 3ll * p;
        __builtin_nontemporal_store(o0, op + 0);
        __builtin_nontemporal_store(o1, op + 1);
        __builtin_nontemporal_store(o2, op + 2);
    }
}

// Tail kernel for odd n (not hit for B=4194304, but keep it correct).
__global__ __launch_bounds__(64) void TacrolimusPK_tail(
    const float* __restrict__ state, const float* __restrict__ Ktr,
    const float* __restrict__ CL, const float* __restrict__ Q,
    const float* __restrict__ Vc, const float* __restrict__ Vp,
    float* __restrict__ out, int start, int n)
{
    int i = start + blockIdx.x * blockDim.x + threadIdx.x;
    if (i >= n) return;
    const float* s = state + 6ll * i;
    float ktr = Ktr[i], cl = CL[i], q = Q[i], vc = Vc[i], vp = Vp[i];
    float rvc = 1.0f / vc;
    float k_elim = cl * rvc, k12 = q * rvc, k21 = q / vp;
    float* o = out + 6ll * i;
    o[0] = -ktr * s[0];
    o[1] = ktr * (s[0] - s[1]);
    o[2] = ktr * (s[1] - s[2]);
    o[3] = ktr * (s[2] - s[3]);
    o[4] = ktr * s[3] - (k_elim + k12) * s[4] + k21 * s[5];
    o[5] = k12 * s[4] - k21 * s[5];
}

extern "C" void kernel_launch(void* const* d_in, const int* in_sizes, int n_in,
                              void* d_out, int out_size, void* d_ws, size_t ws_size,
                              hipStream_t stream) {
    // setup_inputs order: t(0), state(1), Ktr(2), CL(3), Q(4), Vc(5), Vp(6)
    const float* state = (const float*)d_in[1];
    const float* Ktr   = (const float*)d_in[2];
    const float* CL    = (const float*)d_in[3];
    const float* Q     = (const float*)d_in[4];
    const float* Vc    = (const float*)d_in[5];
    const float* Vp    = (const float*)d_in[6];
    float* out = (float*)d_out;

    const int n = in_sizes[2];  // B
    const int nPairs = n / 2;
    const int block = 256;
    int grid = (nPairs + block - 1) / block;  // exact fit: 8192 blocks for B=4M
    if (grid > 0)
        TacrolimusPK_kernel2<<<grid, block, 0, stream>>>(state, Ktr, CL, Q, Vc, Vp, out, nPairs);
    if (n & 1)
        TacrolimusPK_tail<<<1, 64, 0, stream>>>(state, Ktr, CL, Q, Vc, Vp, out, nPairs * 2, n);
}

// Round 4
// 45.191 us; speedup vs baseline: 1.6448x; 1.6448x over previous
//
#include <hip/hip_runtime.h>

// Batched Tacrolimus PK derivative: out[i, :] = f(state[i, :], params[i])
// Memory-bound streaming. 44 B in + 24 B out per row.
// Block = 256 threads = 512 rows. Loads: float4 (state) / float2 (params)
// through cache. Stores: staged via LDS so each wave store instruction
// covers 64 contiguous float4s (full 64B lines), then non-temporal to
// keep the write-only output out of L3 (preserving L3 for the inputs).

typedef float f32x4 __attribute__((ext_vector_type(4)));
typedef float f32x2 __attribute__((ext_vector_type(2)));

__global__ __launch_bounds__(256) void TacrolimusPK_main(
    const float* __restrict__ state,  // [n, 6]
    const float* __restrict__ Ktr,    // [n]
    const float* __restrict__ CL,     // [n]
    const float* __restrict__ Q,      // [n]
    const float* __restrict__ Vc,     // [n]
    const float* __restrict__ Vp,     // [n]
    float* __restrict__ out)          // [n, 6]
{
    __shared__ f32x4 lds[768];  // 512 rows * 6 floats = 768 float4s = 12 KB

    const int t = threadIdx.x;
    const long long p = (long long)blockIdx.x * 256 + t;  // pair index (2 rows)

    const f32x4* sp = reinterpret_cast<const f32x4*>(state) + 3 * p;
    f32x4 a = sp[0];  // r0: A_depot, A_g1, A_g2, A_g3
    f32x4 b = sp[1];  // r0: A_c, A_p | r1: A_depot, A_g1
    f32x4 c = sp[2];  // r1: A_g2, A_g3, A_c, A_p

    f32x2 ktr = reinterpret_cast<const f32x2*>(Ktr)[p];
    f32x2 cl  = reinterpret_cast<const f32x2*>(CL)[p];
    f32x2 q   = reinterpret_cast<const f32x2*>(Q)[p];
    f32x2 vc  = reinterpret_cast<const f32x2*>(Vc)[p];
    f32x2 vp  = reinterpret_cast<const f32x2*>(Vp)[p];

    // row 0
    float rvc0    = 1.0f / vc.x;
    float k_elim0 = cl.x * rvc0;
    float k12_0   = q.x * rvc0;
    float k21_0   = q.x / vp.x;
    f32x4 o0;
    o0.x = -ktr.x * a.x;
    o0.y = ktr.x * (a.x - a.y);
    o0.z = ktr.x * (a.y - a.z);
    o0.w = ktr.x * (a.z - a.w);
    float o1x = ktr.x * a.w - (k_elim0 + k12_0) * b.x + k21_0 * b.y;
    float o1y = k12_0 * b.x - k21_0 * b.y;

    // row 1
    float rvc1    = 1.0f / vc.y;
    float k_elim1 = cl.y * rvc1;
    float k12_1   = q.y * rvc1;
    float k21_1   = q.y / vp.y;
    f32x4 o2;
    float o1z = -ktr.y * b.z;
    float o1w = ktr.y * (b.z - b.w);
    o2.x = ktr.y * (b.w - c.x);
    o2.y = ktr.y * (c.x - c.y);
    o2.z = ktr.y * c.y - (k_elim1 + k12_1) * c.z + k21_1 * c.w;
    o2.w = k12_1 * c.z - k21_1 * c.w;

    f32x4 o1; o1.x = o1x; o1.y = o1y; o1.z = o1z; o1.w = o1w;

    // stage: thread t owns float4s 3t..3t+2 of the block's 768-float4 tile
    lds[3 * t + 0] = o0;
    lds[3 * t + 1] = o1;
    lds[3 * t + 2] = o2;
    __syncthreads();

    // drain: linear float4 order -> each wave instr = 64 contiguous float4s
    f32x4* op = reinterpret_cast<f32x4*>(out) + (long long)blockIdx.x * 768;
    __builtin_nontemporal_store(lds[t +   0], op + t +   0);
    __builtin_nontemporal_store(lds[t + 256], op + t + 256);
    __builtin_nontemporal_store(lds[t + 512], op + t + 512);
}

// Tail: rows [start, n) — scalar, only hit when n % 512 != 0.
__global__ __launch_bounds__(64) void TacrolimusPK_tail(
    const float* __restrict__ state, const float* __restrict__ Ktr,
    const float* __restrict__ CL, const float* __restrict__ Q,
    const float* __restrict__ Vc, const float* __restrict__ Vp,
    float* __restrict__ out, int start, int n)
{
    int i = start + blockIdx.x * blockDim.x + threadIdx.x;
    if (i >= n) return;
    const float* s = state + 6ll * i;
    float ktr = Ktr[i], cl = CL[i], q = Q[i], vc = Vc[i], vp = Vp[i];
    float rvc = 1.0f / vc;
    float k_elim = cl * rvc, k12 = q * rvc, k21 = q / vp;
    float* o = out + 6ll * i;
    o[0] = -ktr * s[0];
    o[1] = ktr * (s[0] - s[1]);
    o[2] = ktr * (s[1] - s[2]);
    o[3] = ktr * (s[2] - s[3]);
    o[4] = ktr * s[3] - (k_elim + k12) * s[4] + k21 * s[5];
    o[5] = k12 * s[4] - k21 * s[5];
}

extern "C" void kernel_launch(void* const* d_in, const int* in_sizes, int n_in,
                              void* d_out, int out_size, void* d_ws, size_t ws_size,
                              hipStream_t stream) {
    // setup_inputs order: t(0), state(1), Ktr(2), CL(3), Q(4), Vc(5), Vp(6)
    const float* state = (const float*)d_in[1];
    const float* Ktr   = (const float*)d_in[2];
    const float* CL    = (const float*)d_in[3];
    const float* Q     = (const float*)d_in[4];
    const float* Vc    = (const float*)d_in[5];
    const float* Vp    = (const float*)d_in[6];
    float* out = (float*)d_out;

    const int n = in_sizes[2];           // B = 4194304
    const int nBlocks = n / 512;         // full blocks (8192 for B=4M)
    if (nBlocks > 0)
        TacrolimusPK_main<<<nBlocks, 256, 0, stream>>>(state, Ktr, CL, Q, Vc, Vp, out);
    const int done = nBlocks * 512;
    if (done < n) {
        int rem = n - done;
        TacrolimusPK_tail<<<(rem + 63) / 64, 64, 0, stream>>>(state, Ktr, CL, Q, Vc, Vp, out, done, n);
    }
}